// Round 1
// baseline (588.794 us; speedup 1.0000x reference)
//
#include <hip/hip_runtime.h>
#include <hip/hip_bf16.h>

// BHLinear on MI355X (gfx950). fp32 I/O (per reference), bf16 MFMA compute.
// Math: per row (64x64 view X), layer = H64 * (X * blockdiag(B_n)) * H64 / 64.
// Fold right-H into weights: C_n = B_n * H / 64 (prepacked as MFMA A-frags, bf16).
// Layer = A-step (per-group GEMM, dual form) + B-step (H-mix, normal form, H in regs).
// Final = per-rect 32x32 GEMM (dual form), fp32 stores straight to global.
// One 16-row tile per 1024-thread WG, single 128KB swizzled bf16 LDS buffer, in-place.
// R1: prep_inner rewritten as wave-FWHT (was 64-load gather per element, ~200us);
//     bh_main 512->1024 threads/WG (8->16 waves/CU) to attack latency-bound phases.

typedef __attribute__((ext_vector_type(8))) short bf16x8;
typedef __attribute__((ext_vector_type(4))) short bf16x4;
typedef __attribute__((ext_vector_type(4))) float f32x4;

#define MFMA16(a, b, c) __builtin_amdgcn_mfma_f32_16x16x32_bf16((a), (b), (c), 0, 0, 0)

__device__ __forceinline__ short f2bf(float f) {
    unsigned int u; __builtin_memcpy(&u, &f, 4);
    u += 0x7FFFu + ((u >> 16) & 1u);   // RNE
    return (short)(u >> 16);
}
// LDS element address for tile element (batch-row b in 0..15, d in 0..4095).
// Quad(8B)-granular XOR swizzle keyed by (b + d>>8): all four access patterns
// (A-read j-contig, A-write i-quad, B-read i-quad @ m-stride, B-write i-quad
// @ b-stride) land at ~floor bank rate. Bijective in (b,d); 8B-aligned for d%4==0.
__device__ __forceinline__ int swz(int b, int d) {
    int key = (b + (d >> 8)) & 15;
    return (b << 12) | (d & 0xFC0) | ((((d >> 2) & 15) ^ key) << 2) | (d & 3);
}

// ---- prepack C_n = B_n * H / 64 (fp32 in, bf16 frags out), dual-form A-operand (C^T).
// C[l,g][j][o] = (1/64) sum_k B[l,g,j,k] * (-1)^popc(k&o)  — a 64-pt Hadamard along k.
// One wave per row j: coalesced 256B load, 6-stage shfl_xor FWHT, one 2B store/lane.
// Frag layout (must match bh_main A-step reads): element e has jj=e&7,
// lane=(e>>3)&63, fid=e>>9 with fid = l*512+g*8+it*2+ks, j = ks*32+((lane>>4)<<3)+jj,
// o = it*16+(lane&15).
__global__ __launch_bounds__(256) void prep_inner(const float* __restrict__ B, short* __restrict__ out) {
    int rid  = blockIdx.x * 4 + (threadIdx.x >> 6);  // row id < 8192 = 2*64*64
    int lane = threadIdx.x & 63;
    float v = B[rid * 64 + lane];                    // B[l][g][j][lane], coalesced
    #pragma unroll
    for (int m = 1; m < 64; m <<= 1) {
        float p = __shfl_xor(v, m, 64);
        v = (lane & m) ? (p - v) : (v + p);          // lane o ends with sum_k B[k]*(-1)^popc(k&o)
    }
    int l = rid >> 12, g = (rid >> 6) & 63, j = rid & 63;
    int o = lane;
    int jj = j & 7, lhi = (j >> 3) & 3, ks = j >> 5;
    int it = o >> 4;
    int lane_dst = lhi * 16 + (o & 15);
    int fid = l * 512 + g * 8 + it * 2 + ks;
    out[(fid * 64 + lane_dst) * 8 + jj] = f2bf(v * 0.015625f);
}

// ---- prepack final_B^T frags (fp32 -> bf16); fid = r*2 + otile
__global__ void prep_final(const float* __restrict__ F, short* __restrict__ out) {
    int e = blockIdx.x * 256 + threadIdx.x;          // < 131072
    int ww = e & 7, lane = (e >> 3) & 63, fid = e >> 9;
    int ot = fid & 1, r = fid >> 1;
    int w = ((lane >> 4) << 3) + ww;
    int o = ot * 16 + (lane & 15);
    out[e] = f2bf(F[(r * 32 + w) * 32 + o]);
}

__global__ __launch_bounds__(1024, 4) void bh_main(
        const float* __restrict__ Xg,
        const short* __restrict__ CW,
        const short* __restrict__ FW,
        float* __restrict__ Og) {
    __shared__ short sm[16 * 4096];                  // 128 KB (gfx950: 160 KB/WG)
    const int tid  = threadIdx.x;
    const int lane = tid & 63;
    const int wave = tid >> 6;                       // 0..15
    const long row0 = (long)blockIdx.x * 16;

    // H64 fragments (B-operand): Hf[ks][nt], el jj -> H[m][n],
    // m = ks*32 + (lane>>4)*8 + jj, n = nt*16 + (lane&15); H[m][n] = (-1)^popc(m&n)
    bf16x8 Hf[2][4];
    {
        int n0 = lane & 15, mb = (lane >> 4) << 3;
        #pragma unroll
        for (int ks = 0; ks < 2; ++ks)
            #pragma unroll
            for (int nt = 0; nt < 4; ++nt) {
                bf16x8 h;
                #pragma unroll
                for (int jj = 0; jj < 8; ++jj) {
                    int m = ks * 32 + mb + jj, n = nt * 16 + n0;
                    h[jj] = (short)((__builtin_popcount(m & n) & 1) ? 0xBF80 : 0x3F80);
                }
                Hf[ks][nt] = h;
            }
    }

    // ---- stage 16 rows into LDS (fp32 -> bf16, swizzled); coalesced 16B global reads.
    // Threads split: half-WG (512 threads) covers a row's 4096 floats, 8 rows per half.
    {
        const float* src = Xg + row0 * 4096;
        const int d   = (tid & 511) * 8;
        const int bb0 = (tid >> 9) * 8;
        #pragma unroll
        for (int bb = 0; bb < 8; ++bb) {
            int b = bb0 + bb;
            f32x4 v0 = *(const f32x4*)(src + (long)b * 4096 + d);
            f32x4 v1 = *(const f32x4*)(src + (long)b * 4096 + d + 4);
            bf16x4 q0 = { f2bf(v0[0]), f2bf(v0[1]), f2bf(v0[2]), f2bf(v0[3]) };
            bf16x4 q1 = { f2bf(v1[0]), f2bf(v1[1]), f2bf(v1[2]), f2bf(v1[3]) };
            *(bf16x4*)(sm + swz(b, d))     = q0;
            *(bf16x4*)(sm + swz(b, d + 4)) = q1;
        }
    }
    __syncthreads();

    #pragma unroll 1
    for (int l = 0; l < 2; ++l) {
        // ---- A-step: Z[b,g,:] = X[b,g,:] @ C_g. Dual form: D[i][b]. In-place per group.
        {
            const int b = lane & 15;
            const int koff = (lane >> 4) << 3;
            const short* Wl = CW + l * 262144;
            #pragma unroll 2
            for (int gi = 0; gi < 4; ++gi) {
                int g = wave * 4 + gi;               // waves own disjoint groups
                bf16x8 wf[4][2];
                #pragma unroll
                for (int it = 0; it < 4; ++it)
                    #pragma unroll
                    for (int ks = 0; ks < 2; ++ks)
                        wf[it][ks] = *(const bf16x8*)(Wl + ((g * 8 + it * 2 + ks) * 64 + lane) * 8);
                bf16x8 xf[2];
                #pragma unroll
                for (int ks = 0; ks < 2; ++ks) {
                    int d = g * 64 + ks * 32 + koff;
                    bf16x4 a0 = *(const bf16x4*)(sm + swz(b, d));
                    bf16x4 a1 = *(const bf16x4*)(sm + swz(b, d + 4));
                    xf[ks] = bf16x8{a0[0],a0[1],a0[2],a0[3],a1[0],a1[1],a1[2],a1[3]};
                }
                #pragma unroll
                for (int it = 0; it < 4; ++it) {
                    f32x4 acc = {0.f, 0.f, 0.f, 0.f};
                    acc = MFMA16(wf[it][0], xf[0], acc);
                    acc = MFMA16(wf[it][1], xf[1], acc);
                    int i0 = it * 16 + ((lane >> 4) << 2);  // 4 consecutive i -> b64 write
                    bf16x4 o4 = { f2bf(acc[0]), f2bf(acc[1]), f2bf(acc[2]), f2bf(acc[3]) };
                    *(bf16x4*)(sm + swz(b, g * 64 + i0)) = o4;
                }
            }
        }
        __syncthreads();

        // ---- B-step: Y[b,n,i] = sum_m H[n,m] Z[b,m,i]. Normal form per i-column,
        // 4 columns (one i-quad) at a time so reads AND writes are b64. In-place per quad.
        {
            const int ba = lane & 15;
            const int moff = (lane >> 4) << 3;
            const int i0 = wave << 2;                // waves own disjoint i-quads
            bf16x4 rd[2][8];
            #pragma unroll
            for (int ks = 0; ks < 2; ++ks)
                #pragma unroll
                for (int mm = 0; mm < 8; ++mm)
                    rd[ks][mm] = *(const bf16x4*)(sm + swz(ba, (ks * 32 + moff + mm) * 64 + i0));
            f32x4 acc[4][4];                          // [column c][ntile]
            #pragma unroll
            for (int c = 0; c < 4; ++c) {
                bf16x8 af0, af1;
                #pragma unroll
                for (int mm = 0; mm < 8; ++mm) { af0[mm] = rd[0][mm][c]; af1[mm] = rd[1][mm][c]; }
                #pragma unroll
                for (int nt = 0; nt < 4; ++nt) {
                    f32x4 a = {0.f, 0.f, 0.f, 0.f};
                    a = MFMA16(af0, Hf[0][nt], a);
                    a = MFMA16(af1, Hf[1][nt], a);
                    acc[c][nt] = a;
                }
            }
            const int n0 = lane & 15;
            const int bq = (lane >> 4) << 2;
            #pragma unroll
            for (int nt = 0; nt < 4; ++nt) {
                int n = nt * 16 + n0;
                #pragma unroll
                for (int q = 0; q < 4; ++q) {
                    int b = bq + q;
                    bf16x4 o4 = { f2bf(acc[0][nt][q]), f2bf(acc[1][nt][q]),
                                  f2bf(acc[2][nt][q]), f2bf(acc[3][nt][q]) };
                    *(bf16x4*)(sm + swz(b, n * 64 + i0)) = o4;
                }
            }
        }
        __syncthreads();
    }

    // ---- final rect layer: O[b, r*32+o] = sum_w Y[b, r*32+w] * F_r[w][o]. Dual form,
    // fp32 16B global stores (lanes {b,b+16,b+32,b+48} cover 64B contiguous per row).
    {
        const int b = lane & 15;
        const int woff = (lane >> 4) << 3;
        float* Orow = Og + (row0 + b) * 4096;
        #pragma unroll 2
        for (int ri = 0; ri < 8; ++ri) {
            int r = wave * 8 + ri;
            bf16x8 wf0 = *(const bf16x8*)(FW + ((r * 2 + 0) * 64 + lane) * 8);
            bf16x8 wf1 = *(const bf16x8*)(FW + ((r * 2 + 1) * 64 + lane) * 8);
            int d = r * 32 + woff;
            bf16x4 a0 = *(const bf16x4*)(sm + swz(b, d));
            bf16x4 a1 = *(const bf16x4*)(sm + swz(b, d + 4));
            bf16x8 xf = {a0[0],a0[1],a0[2],a0[3],a1[0],a1[1],a1[2],a1[3]};
            #pragma unroll
            for (int ot = 0; ot < 2; ++ot) {
                f32x4 acc = {0.f, 0.f, 0.f, 0.f};
                acc = MFMA16(ot ? wf1 : wf0, xf, acc);
                int o0 = ot * 16 + ((lane >> 4) << 2);
                *(f32x4*)(Orow + r * 32 + o0) = acc;
            }
        }
    }
}

extern "C" void kernel_launch(void* const* d_in, const int* in_sizes, int n_in,
                              void* d_out, int out_size, void* d_ws, size_t ws_size,
                              hipStream_t stream) {
    const float* x  = (const float*)d_in[0];   // fp32 [4,4096,4096]
    const float* iB = (const float*)d_in[1];   // fp32 [2,64,64,64]
    const float* fB = (const float*)d_in[2];   // fp32 [128,32,32]
    short* CW = (short*)d_ws;                  // 524288 bf16 els = 1 MB inner-weight frags
    short* FW = CW + 524288;                   // 131072 bf16 els = 256 KB final frags

    prep_inner<<<2048, 256, 0, stream>>>(iB, CW);
    prep_final<<<512, 256, 0, stream>>>(fB, FW);
    bh_main<<<1024, 1024, 0, stream>>>(x, CW, FW, (float*)d_out);
}

// Round 2
// 540.793 us; speedup vs baseline: 1.0888x; 1.0888x over previous
//
#include <hip/hip_runtime.h>
#include <hip/hip_bf16.h>

// BHLinear on MI355X (gfx950). fp32 I/O (per reference), bf16 MFMA compute.
// Math: per row (64x64 view X), layer = H64 * (X * blockdiag(B_n)) * H64 / 64.
// Fold right-H into weights: C_n = B_n * H / 64 (prepacked as MFMA A-frags, bf16).
// Layer = A-step (per-group GEMM, dual form) + B-step (H-mix, normal form, H in regs).
// Final = per-rect 32x32 GEMM (dual form), fp32 stores straight to global.
// One 16-row tile per 512-thread WG, single 128KB swizzled bf16 LDS buffer, in-place.
// R2: persistent WGs (grid=256, 4 contiguous tiles each); next-tile rows 0-7
//     prefetched into 64 VGPRs during compute; raw s_barrier + lgkmcnt(0) instead of
//     __syncthreads so prefetch loads / final stores stay in flight across barriers.
//     (R1 lesson: 1024 thr/WG starved VGPRs -> 280MB scratch traffic; reverted.)

typedef __attribute__((ext_vector_type(8))) short bf16x8;
typedef __attribute__((ext_vector_type(4))) short bf16x4;
typedef __attribute__((ext_vector_type(4))) float f32x4;

#define MFMA16(a, b, c) __builtin_amdgcn_mfma_f32_16x16x32_bf16((a), (b), (c), 0, 0, 0)

// WG barrier that does NOT drain vmcnt: LDS hazards need lgkmcnt(0) only.
// (__syncthreads emits s_waitcnt vmcnt(0) which would kill cross-phase prefetch.)
#define WG_SYNC() do { \
    asm volatile("s_waitcnt lgkmcnt(0)" ::: "memory"); \
    __builtin_amdgcn_s_barrier(); \
} while (0)

__device__ __forceinline__ short f2bf(float f) {
    unsigned int u; __builtin_memcpy(&u, &f, 4);
    u += 0x7FFFu + ((u >> 16) & 1u);   // RNE
    return (short)(u >> 16);
}
// LDS element address for tile element (batch-row b in 0..15, d in 0..4095).
// Quad(8B)-granular XOR swizzle keyed by (b + d>>8): all four access patterns
// (A-read j-contig, A-write i-quad, B-read i-quad @ m-stride, B-write i-quad
// @ b-stride) land at ~floor bank rate. Bijective in (b,d); 8B-aligned for d%4==0.
__device__ __forceinline__ int swz(int b, int d) {
    int key = (b + (d >> 8)) & 15;
    return (b << 12) | (d & 0xFC0) | ((((d >> 2) & 15) ^ key) << 2) | (d & 3);
}

// ---- prepack C_n = B_n * H / 64 (fp32 in, bf16 frags out), dual-form A-operand (C^T).
// C[l,g][j][o] = (1/64) sum_k B[l,g,j,k] * (-1)^popc(k&o)  — a 64-pt Hadamard along k.
// One wave per row j: coalesced 256B load, 6-stage shfl_xor FWHT, one 2B store/lane.
__global__ __launch_bounds__(256) void prep_inner(const float* __restrict__ B, short* __restrict__ out) {
    int rid  = blockIdx.x * 4 + (threadIdx.x >> 6);  // row id < 8192 = 2*64*64
    int lane = threadIdx.x & 63;
    float v = B[rid * 64 + lane];                    // B[l][g][j][lane], coalesced
    #pragma unroll
    for (int m = 1; m < 64; m <<= 1) {
        float p = __shfl_xor(v, m, 64);
        v = (lane & m) ? (p - v) : (v + p);          // lane o: sum_k B[k]*(-1)^popc(k&o)
    }
    int l = rid >> 12, g = (rid >> 6) & 63, j = rid & 63;
    int o = lane;
    int jj = j & 7, lhi = (j >> 3) & 3, ks = j >> 5;
    int it = o >> 4;
    int lane_dst = lhi * 16 + (o & 15);
    int fid = l * 512 + g * 8 + it * 2 + ks;
    out[(fid * 64 + lane_dst) * 8 + jj] = f2bf(v * 0.015625f);
}

// ---- prepack final_B^T frags (fp32 -> bf16); fid = r*2 + otile
__global__ void prep_final(const float* __restrict__ F, short* __restrict__ out) {
    int e = blockIdx.x * 256 + threadIdx.x;          // < 131072
    int ww = e & 7, lane = (e >> 3) & 63, fid = e >> 9;
    int ot = fid & 1, r = fid >> 1;
    int w = ((lane >> 4) << 3) + ww;
    int o = ot * 16 + (lane & 15);
    out[e] = f2bf(F[(r * 32 + w) * 32 + o]);
}

__global__ __launch_bounds__(512, 2) void bh_main(
        const float* __restrict__ Xg,
        const short* __restrict__ CW,
        const short* __restrict__ FW,
        float* __restrict__ Og) {
    __shared__ short sm[16 * 4096];                  // 128 KB (gfx950: 160 KB/WG)
    const int tid  = threadIdx.x;
    const int lane = tid & 63;
    const int wave = tid >> 6;                       // 0..7
    const int d8   = tid * 8;                        // this thread's column in a row

    // H64 fragments (B-operand): Hf[ks][nt], el jj -> H[m][n],
    // m = ks*32 + (lane>>4)*8 + jj, n = nt*16 + (lane&15); H[m][n] = (-1)^popc(m&n)
    bf16x8 Hf[2][4];
    {
        int n0 = lane & 15, mb = (lane >> 4) << 3;
        #pragma unroll
        for (int ks = 0; ks < 2; ++ks)
            #pragma unroll
            for (int nt = 0; nt < 4; ++nt) {
                bf16x8 h;
                #pragma unroll
                for (int jj = 0; jj < 8; ++jj) {
                    int m = ks * 32 + mb + jj, n = nt * 16 + n0;
                    h[jj] = (short)((__builtin_popcount(m & n) & 1) ? 0xBF80 : 0x3F80);
                }
                Hf[ks][nt] = h;
            }
    }

    // ---- prologue: prefetch tile 0, rows 0-7 into registers (64 VGPR)
    f32x4 P[16];
    {
        const float* src0 = Xg + (long)blockIdx.x * 64 * 4096;
        #pragma unroll
        for (int b = 0; b < 8; ++b) {
            P[2*b]   = *(const f32x4*)(src0 + (long)b * 4096 + d8);
            P[2*b+1] = *(const f32x4*)(src0 + (long)b * 4096 + d8 + 4);
        }
    }

    #pragma unroll 1
    for (int t = 0; t < 4; ++t) {
        const long row0 = (long)blockIdx.x * 64 + t * 16;
        const float* src = Xg + row0 * 4096;

        // ---- stage 16 rows into LDS (fp32 -> bf16, swizzled).
        // Rows 0-7 from prefetch regs; rows 8-15 direct (loads issued first for ILP).
        {
            f32x4 V[16];
            #pragma unroll
            for (int b = 8; b < 16; ++b) {
                V[2*(b-8)]   = *(const f32x4*)(src + (long)b * 4096 + d8);
                V[2*(b-8)+1] = *(const f32x4*)(src + (long)b * 4096 + d8 + 4);
            }
            #pragma unroll
            for (int b = 0; b < 8; ++b) {
                f32x4 v0 = P[2*b], v1 = P[2*b+1];
                bf16x4 q0 = { f2bf(v0[0]), f2bf(v0[1]), f2bf(v0[2]), f2bf(v0[3]) };
                bf16x4 q1 = { f2bf(v1[0]), f2bf(v1[1]), f2bf(v1[2]), f2bf(v1[3]) };
                *(bf16x4*)(sm + swz(b, d8))     = q0;
                *(bf16x4*)(sm + swz(b, d8 + 4)) = q1;
            }
            #pragma unroll
            for (int b = 8; b < 16; ++b) {
                f32x4 v0 = V[2*(b-8)], v1 = V[2*(b-8)+1];
                bf16x4 q0 = { f2bf(v0[0]), f2bf(v0[1]), f2bf(v0[2]), f2bf(v0[3]) };
                bf16x4 q1 = { f2bf(v1[0]), f2bf(v1[1]), f2bf(v1[2]), f2bf(v1[3]) };
                *(bf16x4*)(sm + swz(b, d8))     = q0;
                *(bf16x4*)(sm + swz(b, d8 + 4)) = q1;
            }
        }
        WG_SYNC();

        // ---- issue next tile's row 0-7 prefetch; overlaps the whole compute region
        // (raw barriers don't drain vmcnt, so these stay in flight until next stage).
        if (t < 3) {
            const float* srcn = src + 16 * 4096;
            #pragma unroll
            for (int b = 0; b < 8; ++b) {
                P[2*b]   = *(const f32x4*)(srcn + (long)b * 4096 + d8);
                P[2*b+1] = *(const f32x4*)(srcn + (long)b * 4096 + d8 + 4);
            }
        }

        #pragma unroll 1
        for (int l = 0; l < 2; ++l) {
            // ---- A-step: Z[b,g,:] = X[b,g,:] @ C_g. Dual form: D[i][b]. In-place per group.
            {
                const int b = lane & 15;
                const int koff = (lane >> 4) << 3;
                const short* Wl = CW + l * 262144;
                #pragma unroll 2
                for (int gi = 0; gi < 8; ++gi) {
                    int g = wave * 8 + gi;               // waves own disjoint groups
                    bf16x8 wf[4][2];
                    #pragma unroll
                    for (int it = 0; it < 4; ++it)
                        #pragma unroll
                        for (int ks = 0; ks < 2; ++ks)
                            wf[it][ks] = *(const bf16x8*)(Wl + ((g * 8 + it * 2 + ks) * 64 + lane) * 8);
                    bf16x8 xf[2];
                    #pragma unroll
                    for (int ks = 0; ks < 2; ++ks) {
                        int d = g * 64 + ks * 32 + koff;
                        bf16x4 a0 = *(const bf16x4*)(sm + swz(b, d));
                        bf16x4 a1 = *(const bf16x4*)(sm + swz(b, d + 4));
                        xf[ks] = bf16x8{a0[0],a0[1],a0[2],a0[3],a1[0],a1[1],a1[2],a1[3]};
                    }
                    #pragma unroll
                    for (int it = 0; it < 4; ++it) {
                        f32x4 acc = {0.f, 0.f, 0.f, 0.f};
                        acc = MFMA16(wf[it][0], xf[0], acc);
                        acc = MFMA16(wf[it][1], xf[1], acc);
                        int i0 = it * 16 + ((lane >> 4) << 2);  // 4 consecutive i -> b64 write
                        bf16x4 o4 = { f2bf(acc[0]), f2bf(acc[1]), f2bf(acc[2]), f2bf(acc[3]) };
                        *(bf16x4*)(sm + swz(b, g * 64 + i0)) = o4;
                    }
                }
            }
            WG_SYNC();

            // ---- B-step: Y[b,n,i] = sum_m H[n,m] Z[b,m,i]. Normal form per i-column,
            // 4 columns (one i-quad) at a time so reads AND writes are b64. In-place per quad.
            {
                const int ba = lane & 15;
                const int moff = (lane >> 4) << 3;
                #pragma unroll 1
                for (int s = 0; s < 2; ++s) {
                    const int i0 = (wave * 2 + s) << 2;  // waves own disjoint i-quads
                    bf16x4 rd[2][8];
                    #pragma unroll
                    for (int ks = 0; ks < 2; ++ks)
                        #pragma unroll
                        for (int mm = 0; mm < 8; ++mm)
                            rd[ks][mm] = *(const bf16x4*)(sm + swz(ba, (ks * 32 + moff + mm) * 64 + i0));
                    f32x4 acc[4][4];                      // [column c][ntile]
                    #pragma unroll
                    for (int c = 0; c < 4; ++c) {
                        bf16x8 af0, af1;
                        #pragma unroll
                        for (int mm = 0; mm < 8; ++mm) { af0[mm] = rd[0][mm][c]; af1[mm] = rd[1][mm][c]; }
                        #pragma unroll
                        for (int nt = 0; nt < 4; ++nt) {
                            f32x4 a = {0.f, 0.f, 0.f, 0.f};
                            a = MFMA16(af0, Hf[0][nt], a);
                            a = MFMA16(af1, Hf[1][nt], a);
                            acc[c][nt] = a;
                        }
                    }
                    const int n0 = lane & 15;
                    const int bq = (lane >> 4) << 2;
                    #pragma unroll
                    for (int nt = 0; nt < 4; ++nt) {
                        int n = nt * 16 + n0;
                        #pragma unroll
                        for (int q = 0; q < 4; ++q) {
                            int b = bq + q;
                            bf16x4 o4 = { f2bf(acc[0][nt][q]), f2bf(acc[1][nt][q]),
                                          f2bf(acc[2][nt][q]), f2bf(acc[3][nt][q]) };
                            *(bf16x4*)(sm + swz(b, n * 64 + i0)) = o4;
                        }
                    }
                }
            }
            WG_SYNC();
        }

        // ---- final rect layer: O[b, r*32+o] = sum_w Y[b, r*32+w] * F_r[w][o]. Dual form,
        // fp32 16B global stores (lanes {b,b+16,b+32,b+48} cover 64B contiguous per row).
        {
            const int b = lane & 15;
            const int woff = (lane >> 4) << 3;
            float* Orow = Og + (row0 + b) * 4096;
            #pragma unroll 2
            for (int ri = 0; ri < 16; ++ri) {
                int r = wave * 16 + ri;
                bf16x8 wf0 = *(const bf16x8*)(FW + ((r * 2 + 0) * 64 + lane) * 8);
                bf16x8 wf1 = *(const bf16x8*)(FW + ((r * 2 + 1) * 64 + lane) * 8);
                int d = r * 32 + woff;
                bf16x4 a0 = *(const bf16x4*)(sm + swz(b, d));
                bf16x4 a1 = *(const bf16x4*)(sm + swz(b, d + 4));
                bf16x8 xf = {a0[0],a0[1],a0[2],a0[3],a1[0],a1[1],a1[2],a1[3]};
                #pragma unroll
                for (int ot = 0; ot < 2; ++ot) {
                    f32x4 acc = {0.f, 0.f, 0.f, 0.f};
                    acc = MFMA16(ot ? wf1 : wf0, xf, acc);
                    int o0 = ot * 16 + ((lane >> 4) << 2);
                    *(f32x4*)(Orow + r * 32 + o0) = acc;
                }
            }
        }
        WG_SYNC();   // final reads done before next tile's stage overwrites LDS
    }
}

extern "C" void kernel_launch(void* const* d_in, const int* in_sizes, int n_in,
                              void* d_out, int out_size, void* d_ws, size_t ws_size,
                              hipStream_t stream) {
    const float* x  = (const float*)d_in[0];   // fp32 [4,4096,4096]
    const float* iB = (const float*)d_in[1];   // fp32 [2,64,64,64]
    const float* fB = (const float*)d_in[2];   // fp32 [128,32,32]
    short* CW = (short*)d_ws;                  // 524288 bf16 els = 1 MB inner-weight frags
    short* FW = CW + 524288;                   // 131072 bf16 els = 256 KB final frags

    prep_inner<<<2048, 256, 0, stream>>>(iB, CW);
    prep_final<<<512, 256, 0, stream>>>(fB, FW);
    bh_main<<<256, 512, 0, stream>>>(x, CW, FW, (float*)d_out);
}

// Round 3
// 515.280 us; speedup vs baseline: 1.1427x; 1.0495x over previous
//
#include <hip/hip_runtime.h>
#include <hip/hip_bf16.h>

// BHLinear on MI355X (gfx950). fp32 I/O (per reference), bf16 MFMA compute.
// Math: per row (64x64 view X), layer = H64 * (X * blockdiag(B_n)) * H64 / 64.
// Fold right-H into weights: C_n = B_n * H / 64 (prepacked as MFMA A-frags, bf16).
// Layer = A-step (per-group GEMM, dual form) + B-step (H-mix, normal form, H in regs).
// Final = per-rect 32x32 GEMM (dual form), fp32 NT-stores straight to global.
// One 16-row tile per 512-thread WG, single 128KB swizzled bf16 LDS buffer, in-place.
// R3 (from R0 base; R2 persistent-WG regressed and was reverted):
//  - stage->A1 barrier DELETED: stage thread tid writes cols [512*wave,512*wave+512),
//    A-step wave w reads groups 8w..8w+7 = same slice. Exact ownership -> no sync;
//    compiler schedules stage loads + weight loads + MFMA as one region, waves desync.
//  - f2bf via __bf16 cast so compiler emits v_cvt_pk_bf16_f32 (manual RNE bit-twiddle
//    blocked packing; conversions were the largest VALU block).
//  - final stores nontemporal: write-once output stops evicting L3-resident input.

typedef __attribute__((ext_vector_type(8))) short bf16x8;
typedef __attribute__((ext_vector_type(4))) short bf16x4;
typedef __attribute__((ext_vector_type(4))) float f32x4;

#define MFMA16(a, b, c) __builtin_amdgcn_mfma_f32_16x16x32_bf16((a), (b), (c), 0, 0, 0)

__device__ __forceinline__ short f2bf(float f) {
    __bf16 h = (__bf16)f;                // RNE; lowers to v_cvt_pk_bf16_f32 (packable)
    short s; __builtin_memcpy(&s, &h, 2);
    return s;
}
// LDS element address for tile element (batch-row b in 0..15, d in 0..4095).
// Quad(8B)-granular XOR swizzle keyed by (b + d>>8): all four access patterns
// (A-read j-contig, A-write i-quad, B-read i-quad @ m-stride, B-write i-quad
// @ b-stride) land at ~floor bank rate. Bijective in (b,d); 8B-aligned for d%4==0.
__device__ __forceinline__ int swz(int b, int d) {
    int key = (b + (d >> 8)) & 15;
    return (b << 12) | (d & 0xFC0) | ((((d >> 2) & 15) ^ key) << 2) | (d & 3);
}

// ---- prepack C_n = B_n * H / 64 (fp32 in, bf16 frags out), dual-form A-operand (C^T).
// C[l,g][j][o] = (1/64) sum_k B[l,g,j,k] * (-1)^popc(k&o)  — a 64-pt Hadamard along k.
// One wave per row j: coalesced 256B load, 6-stage shfl_xor FWHT, one 2B store/lane.
__global__ __launch_bounds__(256) void prep_inner(const float* __restrict__ B, short* __restrict__ out) {
    int rid  = blockIdx.x * 4 + (threadIdx.x >> 6);  // row id < 8192 = 2*64*64
    int lane = threadIdx.x & 63;
    float v = B[rid * 64 + lane];                    // B[l][g][j][lane], coalesced
    #pragma unroll
    for (int m = 1; m < 64; m <<= 1) {
        float p = __shfl_xor(v, m, 64);
        v = (lane & m) ? (p - v) : (v + p);          // lane o: sum_k B[k]*(-1)^popc(k&o)
    }
    int l = rid >> 12, g = (rid >> 6) & 63, j = rid & 63;
    int o = lane;
    int jj = j & 7, lhi = (j >> 3) & 3, ks = j >> 5;
    int it = o >> 4;
    int lane_dst = lhi * 16 + (o & 15);
    int fid = l * 512 + g * 8 + it * 2 + ks;
    out[(fid * 64 + lane_dst) * 8 + jj] = f2bf(v * 0.015625f);
}

// ---- prepack final_B^T frags (fp32 -> bf16); fid = r*2 + otile
__global__ void prep_final(const float* __restrict__ F, short* __restrict__ out) {
    int e = blockIdx.x * 256 + threadIdx.x;          // < 131072
    int ww = e & 7, lane = (e >> 3) & 63, fid = e >> 9;
    int ot = fid & 1, r = fid >> 1;
    int w = ((lane >> 4) << 3) + ww;
    int o = ot * 16 + (lane & 15);
    out[e] = f2bf(F[(r * 32 + w) * 32 + o]);
}

__global__ __launch_bounds__(512) void bh_main(
        const float* __restrict__ Xg,
        const short* __restrict__ CW,
        const short* __restrict__ FW,
        float* __restrict__ Og) {
    __shared__ short sm[16 * 4096];                  // 128 KB (gfx950: 160 KB/WG)
    const int tid  = threadIdx.x;
    const int lane = tid & 63;
    const int wave = tid >> 6;                       // 0..7
    const long row0 = (long)blockIdx.x * 16;

    // H64 fragments (B-operand): Hf[ks][nt], el jj -> H[m][n],
    // m = ks*32 + (lane>>4)*8 + jj, n = nt*16 + (lane&15); H[m][n] = (-1)^popc(m&n)
    bf16x8 Hf[2][4];
    {
        int n0 = lane & 15, mb = (lane >> 4) << 3;
        #pragma unroll
        for (int ks = 0; ks < 2; ++ks)
            #pragma unroll
            for (int nt = 0; nt < 4; ++nt) {
                bf16x8 h;
                #pragma unroll
                for (int jj = 0; jj < 8; ++jj) {
                    int m = ks * 32 + mb + jj, n = nt * 16 + n0;
                    h[jj] = (short)((__builtin_popcount(m & n) & 1) ? 0xBF80 : 0x3F80);
                }
                Hf[ks][nt] = h;
            }
    }

    // ---- stage 16 rows into LDS (fp32 -> bf16, swizzled); coalesced 16B global reads.
    // Thread tid covers cols [tid*8, tid*8+8) -> wave w writes slice [512w, 512w+512),
    // which is exactly what wave w's A-step (groups 8w..8w+7) reads: NO barrier after.
    {
        const float* src = Xg + row0 * 4096;
        const int d = tid * 8;
        #pragma unroll
        for (int b = 0; b < 16; ++b) {
            f32x4 v0 = *(const f32x4*)(src + (long)b * 4096 + d);
            f32x4 v1 = *(const f32x4*)(src + (long)b * 4096 + d + 4);
            bf16x4 q0 = { f2bf(v0[0]), f2bf(v0[1]), f2bf(v0[2]), f2bf(v0[3]) };
            bf16x4 q1 = { f2bf(v1[0]), f2bf(v1[1]), f2bf(v1[2]), f2bf(v1[3]) };
            *(bf16x4*)(sm + swz(b, d))     = q0;
            *(bf16x4*)(sm + swz(b, d + 4)) = q1;
        }
    }
    // (no __syncthreads: slice ownership proven above; B-step below has its own barrier)

    #pragma unroll 1
    for (int l = 0; l < 2; ++l) {
        // ---- A-step: Z[b,g,:] = X[b,g,:] @ C_g. Dual form: D[i][b]. In-place per group.
        {
            const int b = lane & 15;
            const int koff = (lane >> 4) << 3;
            const short* Wl = CW + l * 262144;
            #pragma unroll 2
            for (int gi = 0; gi < 8; ++gi) {
                int g = wave * 8 + gi;               // waves own disjoint groups
                bf16x8 wf[4][2];
                #pragma unroll
                for (int it = 0; it < 4; ++it)
                    #pragma unroll
                    for (int ks = 0; ks < 2; ++ks)
                        wf[it][ks] = *(const bf16x8*)(Wl + ((g * 8 + it * 2 + ks) * 64 + lane) * 8);
                bf16x8 xf[2];
                #pragma unroll
                for (int ks = 0; ks < 2; ++ks) {
                    int d = g * 64 + ks * 32 + koff;
                    bf16x4 a0 = *(const bf16x4*)(sm + swz(b, d));
                    bf16x4 a1 = *(const bf16x4*)(sm + swz(b, d + 4));
                    xf[ks] = bf16x8{a0[0],a0[1],a0[2],a0[3],a1[0],a1[1],a1[2],a1[3]};
                }
                #pragma unroll
                for (int it = 0; it < 4; ++it) {
                    f32x4 acc = {0.f, 0.f, 0.f, 0.f};
                    acc = MFMA16(wf[it][0], xf[0], acc);
                    acc = MFMA16(wf[it][1], xf[1], acc);
                    int i0 = it * 16 + ((lane >> 4) << 2);  // 4 consecutive i -> b64 write
                    bf16x4 o4 = { f2bf(acc[0]), f2bf(acc[1]), f2bf(acc[2]), f2bf(acc[3]) };
                    *(bf16x4*)(sm + swz(b, g * 64 + i0)) = o4;
                }
            }
        }
        __syncthreads();

        // ---- B-step: Y[b,n,i] = sum_m H[n,m] Z[b,m,i]. Normal form per i-column,
        // 4 columns (one i-quad) at a time so reads AND writes are b64. In-place per quad.
        {
            const int ba = lane & 15;
            const int moff = (lane >> 4) << 3;
            #pragma unroll 1
            for (int s = 0; s < 2; ++s) {
                const int i0 = (wave * 2 + s) << 2;  // waves own disjoint i-quads
                bf16x4 rd[2][8];
                #pragma unroll
                for (int ks = 0; ks < 2; ++ks)
                    #pragma unroll
                    for (int mm = 0; mm < 8; ++mm)
                        rd[ks][mm] = *(const bf16x4*)(sm + swz(ba, (ks * 32 + moff + mm) * 64 + i0));
                f32x4 acc[4][4];                      // [column c][ntile]
                #pragma unroll
                for (int c = 0; c < 4; ++c) {
                    bf16x8 af0, af1;
                    #pragma unroll
                    for (int mm = 0; mm < 8; ++mm) { af0[mm] = rd[0][mm][c]; af1[mm] = rd[1][mm][c]; }
                    #pragma unroll
                    for (int nt = 0; nt < 4; ++nt) {
                        f32x4 a = {0.f, 0.f, 0.f, 0.f};
                        a = MFMA16(af0, Hf[0][nt], a);
                        a = MFMA16(af1, Hf[1][nt], a);
                        acc[c][nt] = a;
                    }
                }
                const int n0 = lane & 15;
                const int bq = (lane >> 4) << 2;
                #pragma unroll
                for (int nt = 0; nt < 4; ++nt) {
                    int n = nt * 16 + n0;
                    #pragma unroll
                    for (int q = 0; q < 4; ++q) {
                        int b = bq + q;
                        bf16x4 o4 = { f2bf(acc[0][nt][q]), f2bf(acc[1][nt][q]),
                                      f2bf(acc[2][nt][q]), f2bf(acc[3][nt][q]) };
                        *(bf16x4*)(sm + swz(b, n * 64 + i0)) = o4;
                    }
                }
            }
        }
        __syncthreads();
    }

    // ---- final rect layer: O[b, r*32+o] = sum_w Y[b, r*32+w] * F_r[w][o]. Dual form,
    // fp32 16B nontemporal global stores (write-once output; keep input L3-resident).
    {
        const int b = lane & 15;
        const int woff = (lane >> 4) << 3;
        float* Orow = Og + (row0 + b) * 4096;
        #pragma unroll 2
        for (int ri = 0; ri < 16; ++ri) {
            int r = wave * 16 + ri;
            bf16x8 wf0 = *(const bf16x8*)(FW + ((r * 2 + 0) * 64 + lane) * 8);
            bf16x8 wf1 = *(const bf16x8*)(FW + ((r * 2 + 1) * 64 + lane) * 8);
            int d = r * 32 + woff;
            bf16x4 a0 = *(const bf16x4*)(sm + swz(b, d));
            bf16x4 a1 = *(const bf16x4*)(sm + swz(b, d + 4));
            bf16x8 xf = {a0[0],a0[1],a0[2],a0[3],a1[0],a1[1],a1[2],a1[3]};
            #pragma unroll
            for (int ot = 0; ot < 2; ++ot) {
                f32x4 acc = {0.f, 0.f, 0.f, 0.f};
                acc = MFMA16(ot ? wf1 : wf0, xf, acc);
                int o0 = ot * 16 + ((lane >> 4) << 2);
                __builtin_nontemporal_store(acc, (f32x4*)(Orow + r * 32 + o0));
            }
        }
    }
}

extern "C" void kernel_launch(void* const* d_in, const int* in_sizes, int n_in,
                              void* d_out, int out_size, void* d_ws, size_t ws_size,
                              hipStream_t stream) {
    const float* x  = (const float*)d_in[0];   // fp32 [4,4096,4096]
    const float* iB = (const float*)d_in[1];   // fp32 [2,64,64,64]
    const float* fB = (const float*)d_in[2];   // fp32 [128,32,32]
    short* CW = (short*)d_ws;                  // 524288 bf16 els = 1 MB inner-weight frags
    short* FW = CW + 524288;                   // 131072 bf16 els = 256 KB final frags

    prep_inner<<<2048, 256, 0, stream>>>(iB, CW);
    prep_final<<<512, 256, 0, stream>>>(fB, FW);
    bh_main<<<1024, 512, 0, stream>>>(x, CW, FW, (float*)d_out);
}